// Round 1
// baseline (484.944 us; speedup 1.0000x reference)
//
#include <hip/hip_runtime.h>

#define B_TOT 131072
#define L_ 9
#define D_ 22
#define H_ 2
#define FF_ 128
#define RPB 28            // rows per block
#define TPB (RPB * L_)    // 252 threads

// ---- workspace layout (floats) ----
#define WS_PE   0      // pe[9][22]                       : 198
#define WS_PB   198    // pbias[h][i][j]                  : 162
#define WS_MT   360    // MT[h][d][c]  = (Wq_h Wk_h^T/sqrt22)[c][d]   : 968
#define WS_VWO  1328   // WVOT[h][d][c]= (Wv_h Wo_h)[c][d]            : 968
#define WS_W1T  2296   // W1T[f][c]    = W1[c][f]                     : 2816
// total 5112 floats = 20448 bytes

__global__ void setup_k(const float* __restrict__ W_rel, const float* __restrict__ b_rel,
                        const float* __restrict__ Wq, const float* __restrict__ Wk,
                        const float* __restrict__ Wv, const float* __restrict__ Wo,
                        const float* __restrict__ W1, const float* __restrict__ Wp,
                        const float* __restrict__ bp, float* __restrict__ ws)
{
    const int t = threadIdx.x;
    // absolute sinusoidal PE: pe[l][d]
    for (int idx = t; idx < 198; idx += 256) {
        int l = idx / 22, d = idx % 22, tt = d / 2;
        float div = __expf((float)(2 * tt) * (-logf(10000.f) / 22.f));
        float ang = (float)l * div;
        ws[WS_PE + idx] = (d & 1) ? cosf(ang) : sinf(ang);
    }
    // relative-position attention bias: pbias[h][i][j]
    for (int idx = t; idx < 162; idx += 256) {
        int h = idx / 81, rem = idx % 81, i = rem / 9, j = rem % 9;
        float s = bp[h];
        for (int d = 0; d < 22; ++d)
            s += (W_rel[(i - j + 9) * 22 + d] + b_rel[d]) * Wp[d * 2 + h];
        ws[WS_PB + idx] = s;
    }
    // MT[h][cp][c] = sum_e Wq[c][h*22+e] * Wk[cp][h*22+e] / sqrt(22)
    for (int idx = t; idx < 968; idx += 256) {
        int h = idx / 484, rem = idx % 484, cp = rem / 22, c = rem % 22;
        float s = 0.f;
        for (int e = 0; e < 22; ++e)
            s += Wq[c * 44 + h * 22 + e] * Wk[cp * 44 + h * 22 + e];
        ws[WS_MT + idx] = s * 0.21320071635561041f; // 1/sqrt(22)
    }
    // WVOT[h][d][c] = sum_e Wv[c][h*22+e] * Wo[h*22+e][d]
    for (int idx = t; idx < 968; idx += 256) {
        int h = idx / 484, rem = idx % 484, d = rem / 22, c = rem % 22;
        float s = 0.f;
        for (int e = 0; e < 22; ++e)
            s += Wv[c * 44 + h * 22 + e] * Wo[(h * 22 + e) * 22 + d];
        ws[WS_VWO + idx] = s;
    }
    // W1T[f][c] = W1[c][f]
    for (int idx = t; idx < 2816; idx += 256) {
        int f = idx / 22, c = idx % 22;
        ws[WS_W1T + idx] = W1[c * 128 + f];
    }
}

__global__ __launch_bounds__(TPB) void fused_model(
    const float* __restrict__ seq, const float* __restrict__ ws,
    const float* __restrict__ g_att, const float* __restrict__ b_att,
    const float* __restrict__ b1, const float* __restrict__ W2,
    const float* __restrict__ b2, const float* __restrict__ g_ff,
    const float* __restrict__ b_ff, const float* __restrict__ W_res,
    const float* __restrict__ b_res, const float* __restrict__ W_out,
    const float* __restrict__ b_out, float* __restrict__ out)
{
    __shared__ __align__(16) float xbuf[RPB][L_][24];   // x after PE, per position
    __shared__ __align__(16) float vwbuf[RPB][L_][24];  // (x_j @ Wvo_h), per head
    __shared__ float red[RPB][L_][2];

    const int tid = threadIdx.x;
    const int r = tid / L_;
    const int i = tid - r * L_;
    const long g = (long)blockIdx.x * RPB + r;
    const bool active = g < B_TOT;
    const long gc = active ? g : (long)(B_TOT - 1);

    // ---- load x = seq_embd + pe ----
    float x[D_];
    {
        const float* xin = seq + gc * (L_ * D_) + i * D_;
        const float* pe  = ws + WS_PE + i * D_;
        #pragma unroll
        for (int c = 0; c < D_; c += 2) {
            float2 t = *reinterpret_cast<const float2*>(xin + c);
            x[c]     = t.x + pe[c];
            x[c + 1] = t.y + pe[c + 1];
        }
    }
    #pragma unroll
    for (int c = 0; c < D_; ++c) xbuf[r][i][c] = x[c];

    float att[D_];
    #pragma unroll
    for (int c = 0; c < D_; ++c) att[c] = 0.f;

    // ---- attention (both heads), fully folded weights ----
    for (int h = 0; h < H_; ++h) {
        const float* MT   = ws + WS_MT  + h * (D_ * D_);
        const float* WVOT = ws + WS_VWO + h * (D_ * D_);
        const float* pb   = ws + WS_PB  + h * (L_ * L_) + i * L_;

        // stage vw_i = x_i @ (Wv_h Wo_h)
        #pragma unroll 2
        for (int d = 0; d < D_; ++d) {
            float s = 0.f;
            #pragma unroll
            for (int c = 0; c < D_; ++c) s += x[c] * WVOT[d * D_ + c];
            vwbuf[r][i][d] = s;
        }
        __syncthreads();

        // qm_i = x_i @ (Wq_h Wk_h^T / sqrt(22))
        float qm[D_];
        #pragma unroll
        for (int d = 0; d < D_; ++d) {
            float s = 0.f;
            #pragma unroll
            for (int c = 0; c < D_; ++c) s += x[c] * MT[d * D_ + c];
            qm[d] = s;
        }

        // scores + softmax over j
        float p[L_];
        float mx = -1e30f;
        #pragma unroll
        for (int j = 0; j < L_; ++j) {
            float s = pb[j];
            #pragma unroll
            for (int c = 0; c < D_; ++c) s += qm[c] * xbuf[r][j][c];
            p[j] = s;
            mx = fmaxf(mx, s);
        }
        float sum = 0.f;
        #pragma unroll
        for (int j = 0; j < L_; ++j) { p[j] = __expf(p[j] - mx); sum += p[j]; }
        const float inv = 1.f / sum;

        // att += sum_j p_j * vw_j   (this IS heads @ Wo, pre-folded)
        #pragma unroll
        for (int j = 0; j < L_; ++j) {
            const float pj = p[j] * inv;
            #pragma unroll
            for (int c = 0; c < D_; ++c) att[c] += pj * vwbuf[r][j][c];
        }
        __syncthreads();
    }

    // ---- LayerNorm 1 (residual) ----
    {
        float s = 0.f;
        #pragma unroll
        for (int c = 0; c < D_; ++c) { x[c] += att[c]; s += x[c]; }
        const float mean = s * (1.f / 22.f);
        float vs = 0.f;
        #pragma unroll
        for (int c = 0; c < D_; ++c) { float d = x[c] - mean; vs += d * d; }
        const float rstd = rsqrtf(vs * (1.f / 22.f) + 1e-5f);
        #pragma unroll
        for (int c = 0; c < D_; ++c) x[c] = (x[c] - mean) * rstd * g_att[c] + b_att[c];
    }

    // ---- feed-forward ----
    float y2[D_];
    #pragma unroll
    for (int c = 0; c < D_; ++c) y2[c] = b2[c];
    {
        const float* W1T = ws + WS_W1T;
        #pragma unroll 4
        for (int f = 0; f < FF_; ++f) {
            float s = b1[f];
            #pragma unroll
            for (int c = 0; c < D_; ++c) s += x[c] * W1T[f * D_ + c];
            s = fmaxf(s, 0.f);
            #pragma unroll
            for (int c = 0; c < D_; ++c) y2[c] += s * W2[f * D_ + c];
        }
    }

    // ---- LayerNorm 2 (residual) ----
    {
        float s = 0.f;
        #pragma unroll
        for (int c = 0; c < D_; ++c) { x[c] += y2[c]; s += x[c]; }
        const float mean = s * (1.f / 22.f);
        float vs = 0.f;
        #pragma unroll
        for (int c = 0; c < D_; ++c) { float d = x[c] - mean; vs += d * d; }
        const float rstd = rsqrtf(vs * (1.f / 22.f) + 1e-5f);
        #pragma unroll
        for (int c = 0; c < D_; ++c) x[c] = (x[c] - mean) * rstd * g_ff[c] + b_ff[c];
    }

    // ---- residue head + output head (reduce over L via LDS) ----
    {
        float pr = b_res[0];
        #pragma unroll
        for (int c = 0; c < D_; ++c) pr += x[c] * W_res[c];
        red[r][i][0] = pr * W_out[i * 2 + 0];
        red[r][i][1] = pr * W_out[i * 2 + 1];
    }
    __syncthreads();
    if (i == 0 && active) {
        float o0 = b_out[0], o1 = b_out[1];
        #pragma unroll
        for (int j = 0; j < L_; ++j) { o0 += red[r][j][0]; o1 += red[r][j][1]; }
        float2 o; o.x = o0; o.y = o1;
        *reinterpret_cast<float2*>(out + g * 2) = o;
    }
}

extern "C" void kernel_launch(void* const* d_in, const int* in_sizes, int n_in,
                              void* d_out, int out_size, void* d_ws, size_t ws_size,
                              hipStream_t stream)
{
    const float* seq   = (const float*)d_in[0];
    const float* W_rel = (const float*)d_in[1];
    const float* b_rel = (const float*)d_in[2];
    const float* Wq    = (const float*)d_in[3];
    const float* Wk    = (const float*)d_in[4];
    const float* Wv    = (const float*)d_in[5];
    const float* Wo    = (const float*)d_in[6];
    const float* g_att = (const float*)d_in[7];
    const float* b_att = (const float*)d_in[8];
    const float* W1    = (const float*)d_in[9];
    const float* b1    = (const float*)d_in[10];
    const float* W2    = (const float*)d_in[11];
    const float* b2    = (const float*)d_in[12];
    const float* Wp    = (const float*)d_in[13];
    const float* bp    = (const float*)d_in[14];
    const float* g_ff  = (const float*)d_in[15];
    const float* b_ff  = (const float*)d_in[16];
    const float* W_res = (const float*)d_in[17];
    const float* b_res = (const float*)d_in[18];
    const float* W_out = (const float*)d_in[19];
    const float* b_out = (const float*)d_in[20];
    float* out = (float*)d_out;
    float* ws  = (float*)d_ws;

    setup_k<<<1, 256, 0, stream>>>(W_rel, b_rel, Wq, Wk, Wv, Wo, W1, Wp, bp, ws);

    const int grid = (B_TOT + RPB - 1) / RPB;
    fused_model<<<grid, TPB, 0, stream>>>(seq, ws, g_att, b_att, b1, W2, b2,
                                          g_ff, b_ff, W_res, b_res, W_out, b_out, out);
}